// Round 3
// baseline (1408.477 us; speedup 1.0000x reference)
//
#include <hip/hip_runtime.h>

// Depthwise 7x7 VALID conv, fp32, NCHW.
// x: (16,256,128,128), w: (256,7,7), out: (16,256,122,122)
// No LDS. Each thread: 4x8 output micro-tile, 10 rows x 7 float2 loads,
// weights in SGPRs, zero bounds checks (edge tiles overlap with identical
// values). __launch_bounds__(256,6) for ~24 waves/CU latency hiding.

#define BATCH 16
#define CHAN  256
#define H_IN  128
#define W_IN  128
#define KS    7
#define H_OUT 122
#define W_OUT 122

#define RB 4           // output rows per thread
#define CB 8           // output cols per thread

typedef float v2f __attribute__((ext_vector_type(2)));

__global__ __launch_bounds__(256, 6)
void dwconv7x7_kernel(const float* __restrict__ x,
                      const float* __restrict__ w,
                      float* __restrict__ out) {
    const int img = blockIdx.y;                 // b*CHAN + c
    const int ch  = img & (CHAN - 1);

    const int tx = threadIdx.x & 15;            // 16 col groups x 8 = 128 cols
    const int ty = threadIdx.x >> 4;            // 16 row groups x 4 = 64 rows

    int ox = tx * CB;                           // output col base
    if (ox > W_OUT - CB) ox = W_OUT - CB;       // 114 (even -> 8B aligned)
    const int y0 = (blockIdx.x == 0) ? 0 : (H_OUT - 64);   // 0 or 58
    const int oy = y0 + ty * RB;                // <= 118; rows oy..oy+3 valid

    // ---- weights: uniform address -> scalar loads into SGPRs ----
    const float* __restrict__ wp = w + ch * (KS * KS);
    float wr[KS * KS];
    #pragma unroll
    for (int i = 0; i < KS * KS; ++i) wr[i] = wp[i];

    // input base: rows oy..oy+9 (<=127), cols ox..ox+13 (<=127) -- in bounds
    const float* __restrict__ xp =
        x + (size_t)img * (H_IN * W_IN) + (size_t)oy * W_IN + ox;

    float acc[RB][CB] = {};

    #pragma unroll
    for (int r = 0; r < RB + KS - 1; ++r) {     // 10 input rows
        const float* row = xp + r * W_IN;
        float win[CB + KS - 1];                 // 14 floats
        #pragma unroll
        for (int j = 0; j < (CB + KS - 1) / 2; ++j) {
            const v2f v = *reinterpret_cast<const v2f*>(row + 2 * j);
            win[2 * j]     = v.x;
            win[2 * j + 1] = v.y;
        }
        #pragma unroll
        for (int i = 0; i < RB; ++i) {
            const int ky = r - i;
            if (ky >= 0 && ky < KS) {
                #pragma unroll
                for (int kx = 0; kx < KS; ++kx) {
                    const float wv = wr[ky * KS + kx];
                    #pragma unroll
                    for (int cc = 0; cc < CB; ++cc)
                        acc[i][cc] = fmaf(win[kx + cc], wv, acc[i][cc]);
                }
            }
        }
    }

    // ---- stores: all in-bounds by construction; nontemporal to spare L3 ----
    float* __restrict__ op =
        out + (size_t)img * (H_OUT * W_OUT) + (size_t)oy * W_OUT + ox;
    #pragma unroll
    for (int i = 0; i < RB; ++i) {
        float* q = op + i * W_OUT;
        #pragma unroll
        for (int j = 0; j < CB / 2; ++j) {
            v2f v;
            v.x = acc[i][2 * j];
            v.y = acc[i][2 * j + 1];
            __builtin_nontemporal_store(v, reinterpret_cast<v2f*>(q) + j);
        }
    }
}

extern "C" void kernel_launch(void* const* d_in, const int* in_sizes, int n_in,
                              void* d_out, int out_size, void* d_ws, size_t ws_size,
                              hipStream_t stream) {
    const float* x = (const float*)d_in[0];
    const float* w = (const float*)d_in[1];
    float* out = (float*)d_out;

    // block = 256 threads covering 128 cols x 64 rows of output
    dim3 grid(2, BATCH * CHAN, 1);   // 2 row-tiles x 4096 images
    dim3 block(256, 1, 1);
    dwconv7x7_kernel<<<grid, block, 0, stream>>>(x, w, out);
}

// Round 4
// 123.003 us; speedup vs baseline: 11.4508x; 11.4508x over previous
//
#include <hip/hip_runtime.h>

// Depthwise 7x7 VALID conv, fp32, NCHW.
// x: (16,256,128,128), w: (256,7,7), out: (16,256,122,122)
// No LDS. Each thread: 4x8 output micro-tile, 10 rows x 7 float2 loads.
// Weights forced into SGPRs via readfirstlane (block-uniform), so the
// inner loop is v_fmac_f32 v,s,v. Zero bounds checks (edge tiles overlap
// with identical values).

#define BATCH 16
#define CHAN  256
#define H_IN  128
#define W_IN  128
#define KS    7
#define H_OUT 122
#define W_OUT 122

#define RB 4           // output rows per thread
#define CB 8           // output cols per thread

typedef float v2f __attribute__((ext_vector_type(2)));

__device__ __forceinline__ float sgpr_broadcast(float v) {
    return __int_as_float(__builtin_amdgcn_readfirstlane(__float_as_int(v)));
}

__global__ __launch_bounds__(256)
void dwconv7x7_kernel(const float* __restrict__ x,
                      const float* __restrict__ w,
                      float* __restrict__ out) {
    const int img = blockIdx.y;                 // b*CHAN + c
    const int ch  = img & (CHAN - 1);

    const int tx = threadIdx.x & 15;            // 16 col groups x 8 = 128 cols
    const int ty = threadIdx.x >> 4;            // 16 row groups x 4 = 64 rows

    int ox = tx * CB;                           // output col base
    if (ox > W_OUT - CB) ox = W_OUT - CB;       // 114 (even -> 8B aligned)
    const int y0 = (blockIdx.x == 0) ? 0 : (H_OUT - 64);   // 0 or 58
    const int oy = y0 + ty * RB;                // <= 118; rows oy..oy+3 valid

    // ---- weights: load once, force into SGPRs (uniform across block) ----
    const float* __restrict__ wp = w + ch * (KS * KS);
    float wr[KS * KS];
    #pragma unroll
    for (int i = 0; i < KS * KS; ++i) wr[i] = sgpr_broadcast(wp[i]);

    // input base: rows oy..oy+9 (<=127), cols ox..ox+13 (<=127) -- in bounds
    const float* __restrict__ xp =
        x + (size_t)img * (H_IN * W_IN) + (size_t)oy * W_IN + ox;

    float acc[RB][CB] = {};

    #pragma unroll
    for (int r = 0; r < RB + KS - 1; ++r) {     // 10 input rows
        const float* row = xp + r * W_IN;
        float win[CB + KS - 1];                 // 14 floats
        #pragma unroll
        for (int j = 0; j < (CB + KS - 1) / 2; ++j) {
            const v2f v = *reinterpret_cast<const v2f*>(row + 2 * j);
            win[2 * j]     = v.x;
            win[2 * j + 1] = v.y;
        }
        #pragma unroll
        for (int i = 0; i < RB; ++i) {
            const int ky = r - i;
            if (ky >= 0 && ky < KS) {
                #pragma unroll
                for (int kx = 0; kx < KS; ++kx) {
                    const float wv = wr[ky * KS + kx];
                    #pragma unroll
                    for (int cc = 0; cc < CB; ++cc)
                        acc[i][cc] = fmaf(win[kx + cc], wv, acc[i][cc]);
                }
            }
        }
    }

    // ---- stores: all in-bounds by construction; nontemporal to spare L3 ----
    float* __restrict__ op =
        out + (size_t)img * (H_OUT * W_OUT) + (size_t)oy * W_OUT + ox;
    #pragma unroll
    for (int i = 0; i < RB; ++i) {
        float* q = op + i * W_OUT;
        #pragma unroll
        for (int j = 0; j < CB / 2; ++j) {
            v2f v;
            v.x = acc[i][2 * j];
            v.y = acc[i][2 * j + 1];
            __builtin_nontemporal_store(v, reinterpret_cast<v2f*>(q) + j);
        }
    }
}

extern "C" void kernel_launch(void* const* d_in, const int* in_sizes, int n_in,
                              void* d_out, int out_size, void* d_ws, size_t ws_size,
                              hipStream_t stream) {
    const float* x = (const float*)d_in[0];
    const float* w = (const float*)d_in[1];
    float* out = (float*)d_out;

    // block = 256 threads covering 128 cols x 64 rows of output
    dim3 grid(2, BATCH * CHAN, 1);   // 2 row-tiles x 4096 images
    dim3 block(256, 1, 1);
    dwconv7x7_kernel<<<grid, block, 0, stream>>>(x, w, out);
}